// Round 9
// baseline (2273.771 us; speedup 1.0000x reference)
//
#include <hip/hip_runtime.h>

// MoE top-2/8: routed bf16-MFMA grouped GEMMs.
// R9: BK=32 => gemm1 LDS 64KB, gemm2 48KB => 2 blocks/CU (was 1). Same
// race-audited 8-phase interleave per 32-wide K-tile; swizzle adapted
// (write g=slot^((lane>>3)&3), read kg^((row>>1)&3)); counted guards
// vmcnt(2) (gemm1) / vmcnt(1) (gemm2, full-A stage at P3), vmcnt(0) tail.

#define N_TOK 8192
#define DIM   1024
#define HID   2048
#define NEXP  8
#define NK    (N_TOK * 2)
#define MAXT2 72    // max 256-row tiles (64 full + 8 partial)
#define MAXT1 136   // max 128-row tiles (128 full + 8 partial)

typedef __attribute__((ext_vector_type(8))) short short8;
typedef __attribute__((ext_vector_type(4))) float f32x4;

#define BARX() __builtin_amdgcn_s_barrier()
#define FEN()  asm volatile("" ::: "memory")
#define VMW2() asm volatile("s_waitcnt vmcnt(2)" ::: "memory")
#define VMW1() asm volatile("s_waitcnt vmcnt(1)" ::: "memory")
#define VMW0() asm volatile("s_waitcnt vmcnt(0)" ::: "memory")
#define PRIO(p) __builtin_amdgcn_s_setprio(p)

static __device__ __forceinline__ unsigned short f2bf(float f) {
  unsigned int u = __float_as_uint(f);
  u += 0x7fffu + ((u >> 16) & 1u);
  return (unsigned short)(u >> 16);
}

static __device__ __forceinline__ void glds16(const void* g, void* l) {
  __builtin_amdgcn_global_load_lds(
      (const __attribute__((address_space(1))) unsigned int*)g,
      (__attribute__((address_space(3))) unsigned int*)l, 16, 0, 0);
}

// ================= prep: W1^T || W2^T || router || zero(out) ================
__device__ __forceinline__ void transpose_tile(const float* __restrict__ s,
                                               unsigned short* __restrict__ d,
                                               int R, int C, int c0, int r0,
                                               unsigned short (*tT)[68]) {
  int tid = threadIdx.x;
  int c = tid & 63, rq = tid >> 6;
#pragma unroll
  for (int q = 0; q < 4; ++q) {
    int rb = q * 16 + rq * 4;
    ushort4 v;
    v.x = f2bf(s[(size_t)(r0 + rb + 0) * C + c0 + c]);
    v.y = f2bf(s[(size_t)(r0 + rb + 1) * C + c0 + c]);
    v.z = f2bf(s[(size_t)(r0 + rb + 2) * C + c0 + c]);
    v.w = f2bf(s[(size_t)(r0 + rb + 3) * C + c0 + c]);
    *(ushort4*)&tT[c][rb] = v;
  }
  __syncthreads();
#pragma unroll
  for (int it = 0; it < 4; ++it) {
    int idx = it * 256 + tid;
    int cc = idx >> 4;
    int r4 = (idx & 15) * 4;
    *(ushort4*)(d + (size_t)(c0 + cc) * R + r0 + r4) = *(const ushort4*)&tT[cc][r4];
  }
}

__global__ __launch_bounds__(256) void prep_k(
    const float* __restrict__ x, const float* __restrict__ Wr,
    const float* __restrict__ W1, const float* __restrict__ W2,
    unsigned short* __restrict__ w1t, unsigned short* __restrict__ w2t,
    unsigned short* __restrict__ xb, int* __restrict__ te,
    float* __restrict__ tg, float* __restrict__ out) {
  __shared__ unsigned short tT[64][68];
  int bid = blockIdx.x;
  if (bid < 8192) {                       // W1 transpose
    int z = bid >> 10, rem = bid & 1023;
    int c0 = (rem & 63) * 64, r0 = (rem >> 6) * 64;
    transpose_tile(W1 + (size_t)z * DIM * 2 * HID,
                   w1t + (size_t)z * DIM * 2 * HID, DIM, 2 * HID, c0, r0, tT);
  } else if (bid < 12288) {               // W2 transpose
    int b2 = bid - 8192;
    int z = b2 >> 9, rem = b2 & 511;
    int c0 = (rem & 15) * 64, r0 = (rem >> 4) * 64;
    transpose_tile(W2 + (size_t)z * HID * DIM,
                   w2t + (size_t)z * HID * DIM, HID, DIM, c0, r0, tT);
  } else if (bid < 14336) {               // router (4 tokens, 1 wave each)
    int n = (bid - 12288) * 4 + (threadIdx.x >> 6);
    int lane = threadIdx.x & 63;
    float z[8];
#pragma unroll
    for (int e = 0; e < 8; ++e) z[e] = 0.f;
    const float* xr = x + (size_t)n * DIM;
    unsigned short* xbr = xb + (size_t)n * DIM;
#pragma unroll 4
    for (int i = 0; i < DIM / 64; ++i) {
      int d = lane + i * 64;
      float xv = xr[d];
      xbr[d] = f2bf(xv);
      float4 w0 = *(const float4*)(Wr + (size_t)d * 8);
      float4 w1 = *(const float4*)(Wr + (size_t)d * 8 + 4);
      z[0] += xv * w0.x; z[1] += xv * w0.y; z[2] += xv * w0.z; z[3] += xv * w0.w;
      z[4] += xv * w1.x; z[5] += xv * w1.y; z[6] += xv * w1.z; z[7] += xv * w1.w;
    }
    for (int off = 32; off; off >>= 1)
#pragma unroll
      for (int e = 0; e < 8; ++e) z[e] += __shfl_down(z[e], off);
    if (lane == 0) {
      int e0 = 0; float v0 = z[0];
#pragma unroll
      for (int e = 1; e < 8; ++e) if (z[e] > v0) { v0 = z[e]; e0 = e; }
      int e1 = -1; float v1 = -3.4e38f;
#pragma unroll
      for (int e = 0; e < 8; ++e) if (e != e0 && z[e] > v1) { v1 = z[e]; e1 = e; }
      float r = expf(v1 - v0);
      float s0 = 1.f / (1.f + r);
      te[n * 2] = e0; te[n * 2 + 1] = e1;
      tg[n * 2] = s0; tg[n * 2 + 1] = r * s0;
    }
  } else {                                // zero out
    int t = bid - 14336;
    float4* o4 = (float4*)out;
    int idx = t * 256 + threadIdx.x;
#pragma unroll
    for (int i = 0; i < 4; ++i) o4[idx + i * 524288] = (float4){0.f, 0.f, 0.f, 0.f};
  }
}

// ===== sortscan: one block; histogram -> offs/tl256/tl128, scatter ==========
__global__ __launch_bounds__(1024) void sortscan_k(
    const int* __restrict__ te, const float* __restrict__ tg,
    int* __restrict__ offs, int* __restrict__ tl256, int* __restrict__ tl128,
    int* __restrict__ rows, float* __restrict__ rowg) {
  __shared__ int hist[8];
  __shared__ int curs[8];
  int tid = threadIdx.x;
  if (tid < 8) hist[tid] = 0;
  __syncthreads();
  for (int i = tid; i < NK; i += 1024) atomicAdd(&hist[te[i]], 1);
  __syncthreads();
  if (tid == 0) {
    int o = 0, t2 = 0, t1 = 0;
    offs[0] = 0; tl256[0] = 0; tl128[0] = 0;
    for (int e = 0; e < NEXP; ++e) {
      curs[e] = o;
      o += hist[e];
      offs[e + 1] = o;
      t2 += (hist[e] + 255) >> 8;
      tl256[e + 1] = t2;
      t1 += (hist[e] + 127) >> 7;
      tl128[e + 1] = t1;
    }
  }
  __syncthreads();
  for (int i = tid; i < NK; i += 1024) {
    int e = te[i];
    int pos = atomicAdd(&curs[e], 1);
    rows[pos] = i >> 1;
    rowg[pos] = tg[i];
  }
}

// ============ 8-phase BMx256 grouped GEMM, BK=32, 2 blocks/CU ===============
// Per K-tile (32 cols): P0 a-lo+b-lo | stage B(T+1).h0; P1 b-hi | B(T+1).h1;
// P2 a-hi | A(T+2).h0 (BM=256); P3 A(T+2).h1 (or full A, BM=128) + guard.
// Guards: BM=256 vmcnt(2); BM=128 vmcnt(1); tail (A-stage skipped) vmcnt(0).
template <int GID, int BM>
__global__ __launch_bounds__(512, 4) void moe_gemm8p(
    const unsigned short* __restrict__ Asrc,
    const unsigned short* __restrict__ Wt,
    const float* __restrict__ bias,
    unsigned short* __restrict__ hb,
    float* __restrict__ out,
    const int* __restrict__ rows,
    const float* __restrict__ rowg,
    const int* __restrict__ offs,
    const int* __restrict__ tl) {
  constexpr int KD = (GID == 0) ? DIM : HID;
  constexpr int NT = KD / 32;          // 32-wide K-tiles
  constexpr int MF = BM / 32;          // m-frags per wave
  constexpr int MH = MF / 2;
  constexpr int ASZ = BM * 32;         // A slab elements (16KB or 8KB)
  constexpr bool AFULL = (BM == 128);  // stage A as one full tile at P3
  // slabs (elements): A-even 0, A-odd ASZ, B-even 2*ASZ, B-odd 2*ASZ+8192
  __shared__ unsigned short smem[2 * ASZ + 2 * 8192];

  int bt = blockIdx.x;
  if (bt >= tl[NEXP]) return;
  int e = 0;
  while (e < NEXP - 1 && bt >= tl[e + 1]) ++e;
  int rt = bt - tl[e];
  int base = offs[e];
  int cntE = offs[e + 1] - base;
  int row0 = rt * BM;
  int jb = blockIdx.y;

  int tid = threadIdx.x, lane = tid & 63, w = tid >> 6;
  int wr = w >> 2, wc = w & 3;

  // ---------- staging: pre-swizzled global k-group ----------
  int g8 = (((lane & 3) ^ ((lane >> 3) & 3)) * 8);
  // B: 2 halves x 1 glds/thread
  const unsigned short* bP[2];
  int bD[2];
#pragma unroll
  for (int hf = 0; hf < 2; ++hf) {
    int rB = hf * 128 + w * 16 + (lane >> 2);
    if (GID == 0) {
      int j0h = jb * 128;
      int hcol = j0h + (rB >> 5) * 16 + (rB & 15);
      int w1row = hcol + ((rB >> 4) & 1) * HID;   // +HID for b-half of swiGLU
      bP[hf] = Wt + ((size_t)e * 2 * HID + w1row) * DIM + g8;
    } else {
      int j0 = jb * 256;
      bP[hf] = Wt + ((size_t)e * DIM + (j0 + rB)) * HID + g8;
    }
    bD[hf] = (hf * 128 + w * 16) * 32;
  }
  // A: 2 halves (BM=256) or 1 full (BM=128), 1 glds/thread
  constexpr int NAH = AFULL ? 1 : 2;
  const unsigned short* aP[NAH];
  int aD[NAH];
#pragma unroll
  for (int hf = 0; hf < NAH; ++hf) {
    int rbA;
    if (AFULL) {
      rbA = w * 16;
    } else {
      int q0 = w * 16;
      rbA = (q0 < 64 ? q0 : q0 + 64) + hf * 64;
    }
    int rA = rbA + (lane >> 2);
    int rr = row0 + rA; rr = rr < cntE ? rr : cntE - 1;
    if (GID == 0) {
      int tok = rows[base + rr];
      aP[hf] = Asrc + (size_t)tok * DIM + g8;
    } else {
      aP[hf] = Asrc + (size_t)(base + rr) * HID + g8;
    }
    aD[hf] = rbA * 32;
  }

  auto stA = [&](int t, int hf) {
    if (t < NT) glds16(aP[hf] + (size_t)t * 32, smem + (t & 1) * ASZ + aD[hf]);
  };
  auto stB = [&](int t, int hf) {
    if (t < NT) glds16(bP[hf] + (size_t)t * 32, smem + 2 * ASZ + (t & 1) * 8192 + bD[hf]);
  };

  // ---------- ds_read offsets: read slot = kg ^ ((row>>1)&3) ----------
  int kg = lane >> 4;
  int koff = ((kg ^ ((lane >> 1) & 3)) * 8);
  unsigned aoff = (unsigned)((wr * (BM / 2) + (lane & 15)) * 32 + koff);
  unsigned boff = (unsigned)((wc * 64 + (lane & 15)) * 32 + koff);

  f32x4 acc[MF][4];
#pragma unroll
  for (int m = 0; m < MF; ++m)
#pragma unroll
    for (int n = 0; n < 4; ++n) acc[m][n] = (f32x4){0.f, 0.f, 0.f, 0.f};

  short8 a[MH], b[4];

#define MFMA_Q(MB, NB)                                                        \
  PRIO(1);                                                                    \
  _Pragma("unroll") for (int m = 0; m < MH; ++m)                              \
  _Pragma("unroll") for (int n = 0; n < 2; ++n)                               \
    acc[(MB) + m][(NB) + n] = __builtin_amdgcn_mfma_f32_16x16x32_bf16(        \
        a[m], b[(NB) + n], acc[(MB) + m][(NB) + n], 0, 0, 0);                 \
  PRIO(0)

  // ---------- prologue: A0, B0, A1; land A0,B0 ----------
  if constexpr (AFULL) {
    stA(0, 0); stB(0, 0); stB(0, 1); stA(1, 0);
    VMW1();
  } else {
    stA(0, 0); stA(0, 1); stB(0, 0); stB(0, 1); stA(1, 0); stA(1, 1);
    VMW2();
  }
  FEN(); BARX(); FEN();

  for (int it = 0; it < NT / 2; ++it) {
#pragma unroll
    for (int half = 0; half < 2; ++half) {
      int Tn = 2 * it + half;
      unsigned Ab = half ? (unsigned)ASZ : 0u;
      unsigned Bb = 2u * ASZ + (half ? 8192u : 0u);
      // ---- P0: a-lo, b-lo; stage B(Tn+1).h0 ----
#pragma unroll
      for (int m = 0; m < MH; ++m)
        a[m] = *(const short8*)(smem + Ab + aoff + m * 512);
#pragma unroll
      for (int n = 0; n < 2; ++n)
        b[n] = *(const short8*)(smem + Bb + boff + n * 512);
      stB(Tn + 1, 0);
      FEN(); BARX(); FEN();
      MFMA_Q(0, 0);
      FEN(); BARX(); FEN();
      // ---- P1: b-hi; stage B(Tn+1).h1 ----
#pragma unroll
      for (int n = 2; n < 4; ++n)
        b[n] = *(const short8*)(smem + Bb + boff + n * 512);
      stB(Tn + 1, 1);
      FEN(); BARX(); FEN();
      MFMA_Q(0, 2);
      FEN(); BARX(); FEN();
      // ---- P2: a-hi; stage A(Tn+2).h0 (split-A only) ----
#pragma unroll
      for (int m = 0; m < MH; ++m)
        a[m] = *(const short8*)(smem + Ab + aoff + (MH + m) * 512);
      if constexpr (!AFULL) stA(Tn + 2, 0);
      FEN(); BARX(); FEN();
      MFMA_Q(MH, 2);
      FEN(); BARX(); FEN();
      // ---- P3: stage A(Tn+2) last piece; MFMA; guard-before-barrier ----
      if constexpr (AFULL) stA(Tn + 2, 0); else stA(Tn + 2, 1);
      FEN(); BARX(); FEN();
      MFMA_Q(MH, 0);
      if (Tn + 2 < NT) {
        if constexpr (AFULL) { VMW1(); } else { VMW2(); }
      } else {
        VMW0();
      }
      FEN(); BARX(); FEN();
    }
  }
#undef MFMA_Q

  // ---------- epilogue ----------
  int rowl = lane >> 4, coll = lane & 15;
  if (GID == 0) {
    int j0h = jb * 128;
#pragma unroll
    for (int pair = 0; pair < 2; ++pair) {
      int hcol = j0h + (2 * wc + pair) * 16 + coll;
      float ba = bias[e * 2 * HID + hcol];
      float bb = bias[e * 2 * HID + HID + hcol];
#pragma unroll
      for (int m = 0; m < MF; ++m)
#pragma unroll
        for (int j = 0; j < 4; ++j) {
          int grow = row0 + wr * (BM / 2) + m * 16 + rowl * 4 + j;
          if (grow < cntE) {
            float av = acc[m][2 * pair][j] + ba;
            float bv = acc[m][2 * pair + 1][j] + bb;
            float hv = av / (1.f + __expf(-av)) * bv;
            hb[(size_t)(base + grow) * HID + hcol] = f2bf(hv);
          }
        }
    }
  } else {
    int j0 = jb * 256;
    float bv[4];
#pragma unroll
    for (int n = 0; n < 4; ++n) bv[n] = bias[e * DIM + j0 + wc * 64 + n * 16 + coll];
#pragma unroll
    for (int m = 0; m < MF; ++m)
#pragma unroll
      for (int j = 0; j < 4; ++j) {
        int grow = row0 + wr * (BM / 2) + m * 16 + rowl * 4 + j;
        if (grow < cntE) {
          int tok = rows[base + grow];
          float g = rowg[base + grow];
#pragma unroll
          for (int n = 0; n < 4; ++n) {
            int col = j0 + wc * 64 + n * 16 + coll;
            atomicAdd(&out[(size_t)tok * DIM + col], g * (acc[m][n][j] + bv[n]));
          }
        }
      }
  }
}

extern "C" void kernel_launch(void* const* d_in, const int* in_sizes, int n_in,
                              void* d_out, int out_size, void* d_ws, size_t ws_size,
                              hipStream_t stream) {
  (void)in_sizes; (void)n_in; (void)out_size;
  const float* x  = (const float*)d_in[0];
  const float* Wr = (const float*)d_in[1];
  const float* W1 = (const float*)d_in[2];
  const float* b1 = (const float*)d_in[3];
  const float* W2 = (const float*)d_in[4];
  const float* b2 = (const float*)d_in[5];
  float* out = (float*)d_out;
  char* ws = (char*)d_ws;

  const size_t o_xb   = 0;
  const size_t o_w1t  = o_xb   + (size_t)N_TOK * DIM * 2;
  const size_t o_w2t  = o_w1t  + (size_t)NEXP * 2 * HID * DIM * 2;
  const size_t o_hb   = o_w2t  + (size_t)NEXP * DIM * HID * 2;
  const size_t o_rows = o_hb   + (size_t)NK * HID * 2;
  const size_t o_rowg = o_rows + (size_t)NK * 4;
  const size_t o_te   = o_rowg + (size_t)NK * 4;
  const size_t o_tg   = o_te   + (size_t)NK * 4;
  const size_t o_offs = o_tg   + (size_t)NK * 4;
  const size_t o_t2   = o_offs + 64;
  const size_t o_t1   = o_t2   + 64;
  const size_t need   = o_t1   + 64;
  if (ws_size < need) return;

  unsigned short* xb  = (unsigned short*)(ws + o_xb);
  unsigned short* w1t = (unsigned short*)(ws + o_w1t);
  unsigned short* w2t = (unsigned short*)(ws + o_w2t);
  unsigned short* hb  = (unsigned short*)(ws + o_hb);
  int*   rows = (int*)(ws + o_rows);
  float* rowg = (float*)(ws + o_rowg);
  int*   te   = (int*)(ws + o_te);
  float* tg   = (float*)(ws + o_tg);
  int*   offs = (int*)(ws + o_offs);
  int*   tl256 = (int*)(ws + o_t2);
  int*   tl128 = (int*)(ws + o_t1);

  prep_k<<<16384, 256, 0, stream>>>(x, Wr, W1, W2, w1t, w2t, xb, te, tg, out);
  sortscan_k<<<1, 1024, 0, stream>>>(te, tg, offs, tl256, tl128, rows, rowg);
  moe_gemm8p<0, 256><<<dim3(MAXT2, HID / 128), 512, 0, stream>>>(
      xb, w1t, b1, hb, nullptr, rows, rowg, offs, tl256);
  moe_gemm8p<1, 128><<<dim3(MAXT1, DIM / 256), 512, 0, stream>>>(
      hb, w2t, b2, nullptr, out, rows, rowg, offs, tl128);
}

// Round 10
// 430.269 us; speedup vs baseline: 5.2845x; 5.2845x over previous
//
#include <hip/hip_runtime.h>

// MoE top-2/8: routed bf16-MFMA grouped GEMMs.
// R10: R9 with launch_bounds fixed (512,2) -- R9's (512,4) capped VGPR at 64
// and spilled acc to scratch (8GB HBM traffic, 10x slowdown). BK=32 tiles:
// gemm1 64KB LDS, gemm2 48KB => 2 blocks/CU at VGPR=128.

#define N_TOK 8192
#define DIM   1024
#define HID   2048
#define NEXP  8
#define NK    (N_TOK * 2)
#define MAXT2 72    // max 256-row tiles (64 full + 8 partial)
#define MAXT1 136   // max 128-row tiles (128 full + 8 partial)

typedef __attribute__((ext_vector_type(8))) short short8;
typedef __attribute__((ext_vector_type(4))) float f32x4;

#define BARX() __builtin_amdgcn_s_barrier()
#define FEN()  asm volatile("" ::: "memory")
#define VMW2() asm volatile("s_waitcnt vmcnt(2)" ::: "memory")
#define VMW1() asm volatile("s_waitcnt vmcnt(1)" ::: "memory")
#define VMW0() asm volatile("s_waitcnt vmcnt(0)" ::: "memory")
#define PRIO(p) __builtin_amdgcn_s_setprio(p)

static __device__ __forceinline__ unsigned short f2bf(float f) {
  unsigned int u = __float_as_uint(f);
  u += 0x7fffu + ((u >> 16) & 1u);
  return (unsigned short)(u >> 16);
}

static __device__ __forceinline__ void glds16(const void* g, void* l) {
  __builtin_amdgcn_global_load_lds(
      (const __attribute__((address_space(1))) unsigned int*)g,
      (__attribute__((address_space(3))) unsigned int*)l, 16, 0, 0);
}

// ================= prep: W1^T || W2^T || router || zero(out) ================
__device__ __forceinline__ void transpose_tile(const float* __restrict__ s,
                                               unsigned short* __restrict__ d,
                                               int R, int C, int c0, int r0,
                                               unsigned short (*tT)[68]) {
  int tid = threadIdx.x;
  int c = tid & 63, rq = tid >> 6;
#pragma unroll
  for (int q = 0; q < 4; ++q) {
    int rb = q * 16 + rq * 4;
    ushort4 v;
    v.x = f2bf(s[(size_t)(r0 + rb + 0) * C + c0 + c]);
    v.y = f2bf(s[(size_t)(r0 + rb + 1) * C + c0 + c]);
    v.z = f2bf(s[(size_t)(r0 + rb + 2) * C + c0 + c]);
    v.w = f2bf(s[(size_t)(r0 + rb + 3) * C + c0 + c]);
    *(ushort4*)&tT[c][rb] = v;
  }
  __syncthreads();
#pragma unroll
  for (int it = 0; it < 4; ++it) {
    int idx = it * 256 + tid;
    int cc = idx >> 4;
    int r4 = (idx & 15) * 4;
    *(ushort4*)(d + (size_t)(c0 + cc) * R + r0 + r4) = *(const ushort4*)&tT[cc][r4];
  }
}

__global__ __launch_bounds__(256) void prep_k(
    const float* __restrict__ x, const float* __restrict__ Wr,
    const float* __restrict__ W1, const float* __restrict__ W2,
    unsigned short* __restrict__ w1t, unsigned short* __restrict__ w2t,
    unsigned short* __restrict__ xb, int* __restrict__ te,
    float* __restrict__ tg, float* __restrict__ out) {
  __shared__ unsigned short tT[64][68];
  int bid = blockIdx.x;
  if (bid < 8192) {                       // W1 transpose
    int z = bid >> 10, rem = bid & 1023;
    int c0 = (rem & 63) * 64, r0 = (rem >> 6) * 64;
    transpose_tile(W1 + (size_t)z * DIM * 2 * HID,
                   w1t + (size_t)z * DIM * 2 * HID, DIM, 2 * HID, c0, r0, tT);
  } else if (bid < 12288) {               // W2 transpose
    int b2 = bid - 8192;
    int z = b2 >> 9, rem = b2 & 511;
    int c0 = (rem & 15) * 64, r0 = (rem >> 4) * 64;
    transpose_tile(W2 + (size_t)z * HID * DIM,
                   w2t + (size_t)z * HID * DIM, HID, DIM, c0, r0, tT);
  } else if (bid < 14336) {               // router (4 tokens, 1 wave each)
    int n = (bid - 12288) * 4 + (threadIdx.x >> 6);
    int lane = threadIdx.x & 63;
    float z[8];
#pragma unroll
    for (int e = 0; e < 8; ++e) z[e] = 0.f;
    const float* xr = x + (size_t)n * DIM;
    unsigned short* xbr = xb + (size_t)n * DIM;
#pragma unroll 4
    for (int i = 0; i < DIM / 64; ++i) {
      int d = lane + i * 64;
      float xv = xr[d];
      xbr[d] = f2bf(xv);
      float4 w0 = *(const float4*)(Wr + (size_t)d * 8);
      float4 w1 = *(const float4*)(Wr + (size_t)d * 8 + 4);
      z[0] += xv * w0.x; z[1] += xv * w0.y; z[2] += xv * w0.z; z[3] += xv * w0.w;
      z[4] += xv * w1.x; z[5] += xv * w1.y; z[6] += xv * w1.z; z[7] += xv * w1.w;
    }
    for (int off = 32; off; off >>= 1)
#pragma unroll
      for (int e = 0; e < 8; ++e) z[e] += __shfl_down(z[e], off);
    if (lane == 0) {
      int e0 = 0; float v0 = z[0];
#pragma unroll
      for (int e = 1; e < 8; ++e) if (z[e] > v0) { v0 = z[e]; e0 = e; }
      int e1 = -1; float v1 = -3.4e38f;
#pragma unroll
      for (int e = 0; e < 8; ++e) if (e != e0 && z[e] > v1) { v1 = z[e]; e1 = e; }
      float r = expf(v1 - v0);
      float s0 = 1.f / (1.f + r);
      te[n * 2] = e0; te[n * 2 + 1] = e1;
      tg[n * 2] = s0; tg[n * 2 + 1] = r * s0;
    }
  } else {                                // zero out
    int t = bid - 14336;
    float4* o4 = (float4*)out;
    int idx = t * 256 + threadIdx.x;
#pragma unroll
    for (int i = 0; i < 4; ++i) o4[idx + i * 524288] = (float4){0.f, 0.f, 0.f, 0.f};
  }
}

// ===== sortscan: one block; histogram -> offs/tl256/tl128, scatter ==========
__global__ __launch_bounds__(1024) void sortscan_k(
    const int* __restrict__ te, const float* __restrict__ tg,
    int* __restrict__ offs, int* __restrict__ tl256, int* __restrict__ tl128,
    int* __restrict__ rows, float* __restrict__ rowg) {
  __shared__ int hist[8];
  __shared__ int curs[8];
  int tid = threadIdx.x;
  if (tid < 8) hist[tid] = 0;
  __syncthreads();
  for (int i = tid; i < NK; i += 1024) atomicAdd(&hist[te[i]], 1);
  __syncthreads();
  if (tid == 0) {
    int o = 0, t2 = 0, t1 = 0;
    offs[0] = 0; tl256[0] = 0; tl128[0] = 0;
    for (int e = 0; e < NEXP; ++e) {
      curs[e] = o;
      o += hist[e];
      offs[e + 1] = o;
      t2 += (hist[e] + 255) >> 8;
      tl256[e + 1] = t2;
      t1 += (hist[e] + 127) >> 7;
      tl128[e + 1] = t1;
    }
  }
  __syncthreads();
  for (int i = tid; i < NK; i += 1024) {
    int e = te[i];
    int pos = atomicAdd(&curs[e], 1);
    rows[pos] = i >> 1;
    rowg[pos] = tg[i];
  }
}

// ============ 8-phase BMx256 grouped GEMM, BK=32, 2 blocks/CU ===============
// Per K-tile (32 cols): P0 a-lo+b-lo | stage B(T+1).h0; P1 b-hi | B(T+1).h1;
// P2 a-hi | A(T+2).h0 (BM=256); P3 A(T+2).h1 (or full A, BM=128) + guard.
// Guards: BM=256 vmcnt(2); BM=128 vmcnt(1); tail (A-stage skipped) vmcnt(0).
template <int GID, int BM>
__global__ __launch_bounds__(512, 2) void moe_gemm8p(
    const unsigned short* __restrict__ Asrc,
    const unsigned short* __restrict__ Wt,
    const float* __restrict__ bias,
    unsigned short* __restrict__ hb,
    float* __restrict__ out,
    const int* __restrict__ rows,
    const float* __restrict__ rowg,
    const int* __restrict__ offs,
    const int* __restrict__ tl) {
  constexpr int KD = (GID == 0) ? DIM : HID;
  constexpr int NT = KD / 32;          // 32-wide K-tiles
  constexpr int MF = BM / 32;          // m-frags per wave
  constexpr int MH = MF / 2;
  constexpr int ASZ = BM * 32;         // A slab elements (16KB or 8KB)
  constexpr bool AFULL = (BM == 128);  // stage A as one full tile at P3
  // slabs (elements): A-even 0, A-odd ASZ, B-even 2*ASZ, B-odd 2*ASZ+8192
  __shared__ unsigned short smem[2 * ASZ + 2 * 8192];

  int bt = blockIdx.x;
  if (bt >= tl[NEXP]) return;
  int e = 0;
  while (e < NEXP - 1 && bt >= tl[e + 1]) ++e;
  int rt = bt - tl[e];
  int base = offs[e];
  int cntE = offs[e + 1] - base;
  int row0 = rt * BM;
  int jb = blockIdx.y;

  int tid = threadIdx.x, lane = tid & 63, w = tid >> 6;
  int wr = w >> 2, wc = w & 3;

  // ---------- staging: pre-swizzled global k-group ----------
  int g8 = (((lane & 3) ^ ((lane >> 3) & 3)) * 8);
  // B: 2 halves x 1 glds/thread
  const unsigned short* bP[2];
  int bD[2];
#pragma unroll
  for (int hf = 0; hf < 2; ++hf) {
    int rB = hf * 128 + w * 16 + (lane >> 2);
    if (GID == 0) {
      int j0h = jb * 128;
      int hcol = j0h + (rB >> 5) * 16 + (rB & 15);
      int w1row = hcol + ((rB >> 4) & 1) * HID;   // +HID for b-half of swiGLU
      bP[hf] = Wt + ((size_t)e * 2 * HID + w1row) * DIM + g8;
    } else {
      int j0 = jb * 256;
      bP[hf] = Wt + ((size_t)e * DIM + (j0 + rB)) * HID + g8;
    }
    bD[hf] = (hf * 128 + w * 16) * 32;
  }
  // A: 2 halves (BM=256) or 1 full (BM=128), 1 glds/thread
  constexpr int NAH = AFULL ? 1 : 2;
  const unsigned short* aP[NAH];
  int aD[NAH];
#pragma unroll
  for (int hf = 0; hf < NAH; ++hf) {
    int rbA;
    if (AFULL) {
      rbA = w * 16;
    } else {
      int q0 = w * 16;
      rbA = (q0 < 64 ? q0 : q0 + 64) + hf * 64;
    }
    int rA = rbA + (lane >> 2);
    int rr = row0 + rA; rr = rr < cntE ? rr : cntE - 1;
    if (GID == 0) {
      int tok = rows[base + rr];
      aP[hf] = Asrc + (size_t)tok * DIM + g8;
    } else {
      aP[hf] = Asrc + (size_t)(base + rr) * HID + g8;
    }
    aD[hf] = rbA * 32;
  }

  auto stA = [&](int t, int hf) {
    if (t < NT) glds16(aP[hf] + (size_t)t * 32, smem + (t & 1) * ASZ + aD[hf]);
  };
  auto stB = [&](int t, int hf) {
    if (t < NT) glds16(bP[hf] + (size_t)t * 32, smem + 2 * ASZ + (t & 1) * 8192 + bD[hf]);
  };

  // ---------- ds_read offsets: read slot = kg ^ ((row>>1)&3) ----------
  int kg = lane >> 4;
  int koff = ((kg ^ ((lane >> 1) & 3)) * 8);
  unsigned aoff = (unsigned)((wr * (BM / 2) + (lane & 15)) * 32 + koff);
  unsigned boff = (unsigned)((wc * 64 + (lane & 15)) * 32 + koff);

  f32x4 acc[MF][4];
#pragma unroll
  for (int m = 0; m < MF; ++m)
#pragma unroll
    for (int n = 0; n < 4; ++n) acc[m][n] = (f32x4){0.f, 0.f, 0.f, 0.f};

  short8 a[MH], b[4];

#define MFMA_Q(MB, NB)                                                        \
  PRIO(1);                                                                    \
  _Pragma("unroll") for (int m = 0; m < MH; ++m)                              \
  _Pragma("unroll") for (int n = 0; n < 2; ++n)                               \
    acc[(MB) + m][(NB) + n] = __builtin_amdgcn_mfma_f32_16x16x32_bf16(        \
        a[m], b[(NB) + n], acc[(MB) + m][(NB) + n], 0, 0, 0);                 \
  PRIO(0)

  // ---------- prologue: A0, B0, A1; land A0,B0 ----------
  if constexpr (AFULL) {
    stA(0, 0); stB(0, 0); stB(0, 1); stA(1, 0);
    VMW1();
  } else {
    stA(0, 0); stA(0, 1); stB(0, 0); stB(0, 1); stA(1, 0); stA(1, 1);
    VMW2();
  }
  FEN(); BARX(); FEN();

  for (int it = 0; it < NT / 2; ++it) {
#pragma unroll
    for (int half = 0; half < 2; ++half) {
      int Tn = 2 * it + half;
      unsigned Ab = half ? (unsigned)ASZ : 0u;
      unsigned Bb = 2u * ASZ + (half ? 8192u : 0u);
      // ---- P0: a-lo, b-lo; stage B(Tn+1).h0 ----
#pragma unroll
      for (int m = 0; m < MH; ++m)
        a[m] = *(const short8*)(smem + Ab + aoff + m * 512);
#pragma unroll
      for (int n = 0; n < 2; ++n)
        b[n] = *(const short8*)(smem + Bb + boff + n * 512);
      stB(Tn + 1, 0);
      FEN(); BARX(); FEN();
      MFMA_Q(0, 0);
      FEN(); BARX(); FEN();
      // ---- P1: b-hi; stage B(Tn+1).h1 ----
#pragma unroll
      for (int n = 2; n < 4; ++n)
        b[n] = *(const short8*)(smem + Bb + boff + n * 512);
      stB(Tn + 1, 1);
      FEN(); BARX(); FEN();
      MFMA_Q(0, 2);
      FEN(); BARX(); FEN();
      // ---- P2: a-hi; stage A(Tn+2).h0 (split-A only) ----
#pragma unroll
      for (int m = 0; m < MH; ++m)
        a[m] = *(const short8*)(smem + Ab + aoff + (MH + m) * 512);
      if constexpr (!AFULL) stA(Tn + 2, 0);
      FEN(); BARX(); FEN();
      MFMA_Q(MH, 2);
      FEN(); BARX(); FEN();
      // ---- P3: stage A(Tn+2) last piece; MFMA; guard-before-barrier ----
      if constexpr (AFULL) stA(Tn + 2, 0); else stA(Tn + 2, 1);
      FEN(); BARX(); FEN();
      MFMA_Q(MH, 0);
      if (Tn + 2 < NT) {
        if constexpr (AFULL) { VMW1(); } else { VMW2(); }
      } else {
        VMW0();
      }
      FEN(); BARX(); FEN();
    }
  }
#undef MFMA_Q

  // ---------- epilogue ----------
  int rowl = lane >> 4, coll = lane & 15;
  if (GID == 0) {
    int j0h = jb * 128;
#pragma unroll
    for (int pair = 0; pair < 2; ++pair) {
      int hcol = j0h + (2 * wc + pair) * 16 + coll;
      float ba = bias[e * 2 * HID + hcol];
      float bb = bias[e * 2 * HID + HID + hcol];
#pragma unroll
      for (int m = 0; m < MF; ++m)
#pragma unroll
        for (int j = 0; j < 4; ++j) {
          int grow = row0 + wr * (BM / 2) + m * 16 + rowl * 4 + j;
          if (grow < cntE) {
            float av = acc[m][2 * pair][j] + ba;
            float bv = acc[m][2 * pair + 1][j] + bb;
            float hv = av / (1.f + __expf(-av)) * bv;
            hb[(size_t)(base + grow) * HID + hcol] = f2bf(hv);
          }
        }
    }
  } else {
    int j0 = jb * 256;
    float bv[4];
#pragma unroll
    for (int n = 0; n < 4; ++n) bv[n] = bias[e * DIM + j0 + wc * 64 + n * 16 + coll];
#pragma unroll
    for (int m = 0; m < MF; ++m)
#pragma unroll
      for (int j = 0; j < 4; ++j) {
        int grow = row0 + wr * (BM / 2) + m * 16 + rowl * 4 + j;
        if (grow < cntE) {
          int tok = rows[base + grow];
          float g = rowg[base + grow];
#pragma unroll
          for (int n = 0; n < 4; ++n) {
            int col = j0 + wc * 64 + n * 16 + coll;
            atomicAdd(&out[(size_t)tok * DIM + col], g * (acc[m][n][j] + bv[n]));
          }
        }
      }
  }
}

extern "C" void kernel_launch(void* const* d_in, const int* in_sizes, int n_in,
                              void* d_out, int out_size, void* d_ws, size_t ws_size,
                              hipStream_t stream) {
  (void)in_sizes; (void)n_in; (void)out_size;
  const float* x  = (const float*)d_in[0];
  const float* Wr = (const float*)d_in[1];
  const float* W1 = (const float*)d_in[2];
  const float* b1 = (const float*)d_in[3];
  const float* W2 = (const float*)d_in[4];
  const float* b2 = (const float*)d_in[5];
  float* out = (float*)d_out;
  char* ws = (char*)d_ws;

  const size_t o_xb   = 0;
  const size_t o_w1t  = o_xb   + (size_t)N_TOK * DIM * 2;
  const size_t o_w2t  = o_w1t  + (size_t)NEXP * 2 * HID * DIM * 2;
  const size_t o_hb   = o_w2t  + (size_t)NEXP * DIM * HID * 2;
  const size_t o_rows = o_hb   + (size_t)NK * HID * 2;
  const size_t o_rowg = o_rows + (size_t)NK * 4;
  const size_t o_te   = o_rowg + (size_t)NK * 4;
  const size_t o_tg   = o_te   + (size_t)NK * 4;
  const size_t o_offs = o_tg   + (size_t)NK * 4;
  const size_t o_t2   = o_offs + 64;
  const size_t o_t1   = o_t2   + 64;
  const size_t need   = o_t1   + 64;
  if (ws_size < need) return;

  unsigned short* xb  = (unsigned short*)(ws + o_xb);
  unsigned short* w1t = (unsigned short*)(ws + o_w1t);
  unsigned short* w2t = (unsigned short*)(ws + o_w2t);
  unsigned short* hb  = (unsigned short*)(ws + o_hb);
  int*   rows = (int*)(ws + o_rows);
  float* rowg = (float*)(ws + o_rowg);
  int*   te   = (int*)(ws + o_te);
  float* tg   = (float*)(ws + o_tg);
  int*   offs = (int*)(ws + o_offs);
  int*   tl256 = (int*)(ws + o_t2);
  int*   tl128 = (int*)(ws + o_t1);

  prep_k<<<16384, 256, 0, stream>>>(x, Wr, W1, W2, w1t, w2t, xb, te, tg, out);
  sortscan_k<<<1, 1024, 0, stream>>>(te, tg, offs, tl256, tl128, rows, rowg);
  moe_gemm8p<0, 256><<<dim3(MAXT2, HID / 128), 512, 0, stream>>>(
      xb, w1t, b1, hb, nullptr, rows, rowg, offs, tl256);
  moe_gemm8p<1, 128><<<dim3(MAXT1, DIM / 256), 512, 0, stream>>>(
      hb, w2t, b2, nullptr, out, rows, rowg, offs, tl128);
}